// Round 1
// baseline (3000.527 us; speedup 1.0000x reference)
//
#include <hip/hip_runtime.h>
#include <hip/hip_bf16.h>
#include <math.h>

#define NN 32000        // total nodes
#define EE 640000       // edges
#define HH 3            // heads
#define CC 128          // hidden
#define HC 384          // H*C
#define FIN 1038
#define BB 16           // graphs
#define NPG 2000
#define KK 400

// ---------------- workspace layout (float elements) ----------------
#define XL_OFF     0u
#define XR_OFF     12288000u
#define HBN_OFF    24576000u
#define SSRC_OFF   28672000u
#define SEA_OFF    29312000u
#define CNT_OFF    30592000u
#define OFFS_OFF   30624000u
#define CUR_OFF    30656064u
#define R_OFF      30688064u
#define REL_OFF    30720064u
#define SCORE_OFF  30752064u
#define BNSUM_OFF  30784064u
#define BNSQ_OFF   30784192u
#define SCALE_OFF  30784320u
#define SHIFT_OFF  30784448u
#define MEANEA_OFF 30784576u
#define XB_OFF     30784640u

// ---------------- edge-attr mean reduction ----------------
__global__ __launch_bounds__(256) void k_eamean(const float* __restrict__ ea, float* __restrict__ meanea) {
    int tid = threadIdx.x;
    float s0 = 0.f, s1 = 0.f;
    for (int e = blockIdx.x * 256 + tid; e < EE; e += 256 * 256) {
        float2 t = ((const float2*)ea)[e];
        s0 += t.x; s1 += t.y;
    }
    __shared__ float r0[256], r1[256];
    r0[tid] = s0; r1[tid] = s1; __syncthreads();
    for (int st = 128; st; st >>= 1) {
        if (tid < st) { r0[tid] += r0[tid + st]; r1[tid] += r1[tid + st]; }
        __syncthreads();
    }
    if (tid == 0) { atomicAdd(&meanea[0], r0[0]); atomicAdd(&meanea[1], r1[0]); }
}

// ---------------- histogram of dst ----------------
__global__ __launch_bounds__(256) void k_hist(const int* __restrict__ ei, int* __restrict__ cnt) {
    int e = blockIdx.x * 256 + threadIdx.x;
    if (e < EE) atomicAdd(&cnt[ei[EE + e]], 1);
}

// ---------------- exclusive scan over 32000 counters ----------------
__global__ __launch_bounds__(1024) void k_scan(const int* __restrict__ cnt, int* __restrict__ offs, int* __restrict__ cur) {
    __shared__ int sb[1024];
    int tid = threadIdx.x;
    int base = tid * 32;
    int s = 0;
    for (int i = 0; i < 32; i++) { int idx = base + i; s += (idx < NN) ? cnt[idx] : 0; }
    sb[tid] = s; __syncthreads();
    for (int off = 1; off < 1024; off <<= 1) {
        int v = (tid >= off) ? sb[tid - off] : 0;
        __syncthreads();
        sb[tid] += v;
        __syncthreads();
    }
    int run = sb[tid] - s;  // exclusive prefix
    for (int i = 0; i < 32; i++) {
        int idx = base + i;
        if (idx < NN) { int c = cnt[idx]; offs[idx] = run; cur[idx] = run; run += c; }
    }
    if (tid == 1023) offs[NN] = run;
}

// ---------------- scatter edges sorted by dst ----------------
__global__ __launch_bounds__(256) void k_scatter(const int* __restrict__ ei, const float* __restrict__ ea,
                                                 int* __restrict__ cur, int* __restrict__ ssrc, float2* __restrict__ sea) {
    int e = blockIdx.x * 256 + threadIdx.x;
    if (e < EE) {
        int d = ei[EE + e];
        int p = atomicAdd(&cur[d], 1);
        ssrc[p] = ei[e];
        sea[p] = ((const float2*)ea)[e];
    }
}

// ---------------- fp32 tiled GEMM: C[M,HC] = A[M,FIN] @ W[FIN,HC] (+bias) ----------------
__global__ __launch_bounds__(256) void k_gemm(const float* __restrict__ A, const float* __restrict__ W,
                                              const float* __restrict__ bias, float* __restrict__ C) {
    __shared__ float As[16][68];
    __shared__ float Bs[16][64];
    int tid = threadIdx.x;
    int bn = blockIdx.x * 64, bm = blockIdx.y * 64;
    int tm = (tid >> 4) * 4;
    int tn = (tid & 15) * 4;
    int la_m = tid >> 2;
    int la_k = (tid & 3) * 4;
    int lb_n = tid & 63;
    int lb_k = tid >> 6;
    float acc[4][4] = {};
    for (int k0 = 0; k0 < FIN; k0 += 16) {
        __syncthreads();
        const float* ap = A + (size_t)(bm + la_m) * FIN + k0 + la_k;
#pragma unroll
        for (int i = 0; i < 4; i++) {
            int kg = k0 + la_k + i;
            As[la_k + i][la_m] = (kg < FIN) ? ap[i] : 0.f;
        }
#pragma unroll
        for (int i = 0; i < 4; i++) {
            int kg = k0 + lb_k + i * 4;
            Bs[lb_k + i * 4][lb_n] = (kg < FIN) ? W[(size_t)kg * HC + bn + lb_n] : 0.f;
        }
        __syncthreads();
#pragma unroll
        for (int kk = 0; kk < 16; kk++) {
            float4 a4 = *(const float4*)&As[kk][tm];
            float4 b4 = *(const float4*)&Bs[kk][tn];
            float ar[4] = {a4.x, a4.y, a4.z, a4.w};
            float br[4] = {b4.x, b4.y, b4.z, b4.w};
#pragma unroll
            for (int i = 0; i < 4; i++)
#pragma unroll
                for (int j = 0; j < 4; j++)
                    acc[i][j] += ar[i] * br[j];
        }
    }
#pragma unroll
    for (int i = 0; i < 4; i++) {
        float4 o;
        float b0 = bias ? bias[bn + tn + 0] : 0.f;
        float b1 = bias ? bias[bn + tn + 1] : 0.f;
        float b2 = bias ? bias[bn + tn + 2] : 0.f;
        float b3 = bias ? bias[bn + tn + 3] : 0.f;
        o.x = acc[i][0] + b0; o.y = acc[i][1] + b1; o.z = acc[i][2] + b2; o.w = acc[i][3] + b3;
        *(float4*)&C[(size_t)(bm + tm + i) * HC + bn + tn] = o;
    }
}

// ---------------- fused GATv2 per-dst aggregation (one wave per node) ----------------
__global__ __launch_bounds__(256) void k_gat(const float* __restrict__ xl, const float* __restrict__ xr,
                                             const int* __restrict__ offs, const int* __restrict__ ssrc,
                                             const float2* __restrict__ sea, const float* __restrict__ meanea,
                                             const float* __restrict__ We, const float* __restrict__ att,
                                             const float* __restrict__ conv_bias, float* __restrict__ hout) {
    int wave = (blockIdx.x * 256 + threadIdx.x) >> 6;
    int lane = threadIdx.x & 63;
    if (wave >= NN) return;
    float we0[6], we1[6], attv[6], xrv[6];
#pragma unroll
    for (int j = 0; j < 6; j++) {
        int i = j * 64 + lane;
        we0[j] = We[i]; we1[j] = We[HC + i]; attv[j] = att[i];
        xrv[j] = xr[(size_t)wave * HC + i];
    }
    float me0 = meanea[0] * (1.0f / EE), me1 = meanea[1] * (1.0f / EE);
    float acc[6] = {0, 0, 0, 0, 0, 0};
    float den0 = 0, den1 = 0, den2 = 0;
    int p0 = offs[wave], p1 = offs[wave + 1];
    for (int p = p0 - 1; p < p1; ++p) {
        int s; float ea0, ea1;
        if (p < p0) { s = wave; ea0 = me0; ea1 = me1; }   // self loop (fill='mean')
        else { s = ssrc[p]; float2 t = sea[p]; ea0 = t.x; ea1 = t.y; }
        const float* xls = xl + (size_t)s * HC;
        float xv[6], pr0 = 0, pr1 = 0, pr2 = 0;
#pragma unroll
        for (int j = 0; j < 6; j++) {
            float v = xls[j * 64 + lane];
            xv[j] = v;
            float m = v + xrv[j] + ea0 * we0[j] + ea1 * we1[j];
            float t = (m > 0.f) ? m : 0.2f * m;
            float c = t * attv[j];
            if (j < 2) pr0 += c; else if (j < 4) pr1 += c; else pr2 += c;
        }
#pragma unroll
        for (int mask = 32; mask; mask >>= 1) {
            pr0 += __shfl_xor(pr0, mask);
            pr1 += __shfl_xor(pr1, mask);
            pr2 += __shfl_xor(pr2, mask);
        }
        float w0 = __expf(pr0), w1 = __expf(pr1), w2 = __expf(pr2);
        den0 += w0; den1 += w1; den2 += w2;
        acc[0] += w0 * xv[0]; acc[1] += w0 * xv[1];
        acc[2] += w1 * xv[2]; acc[3] += w1 * xv[3];
        acc[4] += w2 * xv[4]; acc[5] += w2 * xv[5];
    }
    float i0 = 1.f / den0, i1 = 1.f / den1, i2 = 1.f / den2;
    float o0 = (acc[0] * i0 + acc[2] * i1 + acc[4] * i2) * (1.f / 3.f) + conv_bias[lane];
    float o1 = (acc[1] * i0 + acc[3] * i1 + acc[5] * i2) * (1.f / 3.f) + conv_bias[64 + lane];
    o0 = (o0 > 0.f) ? o0 : 0.1f * o0;
    o1 = (o1 > 0.f) ? o1 : 0.1f * o1;
    hout[(size_t)wave * CC + lane] = o0;
    hout[(size_t)wave * CC + 64 + lane] = o1;
}

// ---------------- batchnorm stats ----------------
__global__ __launch_bounds__(256) void k_bnstats(const float* __restrict__ h, float* __restrict__ bnsum, float* __restrict__ bnsq) {
    int c = threadIdx.x & 127;
    int row0 = blockIdx.x * 2 + (threadIdx.x >> 7);
    float s = 0.f, ss = 0.f;
    for (int n = row0; n < NN; n += gridDim.x * 2) {
        float v = h[(size_t)n * CC + c];
        s += v; ss += v * v;
    }
    atomicAdd(&bnsum[c], s);
    atomicAdd(&bnsq[c], ss);
}

__global__ __launch_bounds__(128) void k_bnfinal(const float* __restrict__ bnsum, const float* __restrict__ bnsq,
                                                 const float* __restrict__ gamma, const float* __restrict__ beta,
                                                 float* __restrict__ scale, float* __restrict__ shift) {
    int c = threadIdx.x;
    float mu = bnsum[c] * (1.f / NN);
    float var = bnsq[c] * (1.f / NN) - mu * mu;
    float sc = gamma[c] * rsqrtf(var + 1e-5f);
    scale[c] = sc;
    shift[c] = beta[c] - mu * sc;
}

// ---------------- BN apply + scorer dot products (wave per node) ----------------
__global__ __launch_bounds__(256) void k_bnapply(float* __restrict__ h, const float* __restrict__ scale,
                                                 const float* __restrict__ shift, const float* __restrict__ wroot,
                                                 const float* __restrict__ wrel, float* __restrict__ r_, float* __restrict__ rel_) {
    int wave = (blockIdx.x * 256 + threadIdx.x) >> 6;
    int lane = threadIdx.x & 63;
    if (wave >= NN) return;
    size_t base = (size_t)wave * CC;
    float v0 = h[base + lane], v1 = h[base + 64 + lane];
    v0 = v0 * scale[lane] + shift[lane];
    v1 = v1 * scale[64 + lane] + shift[64 + lane];
    h[base + lane] = v0;
    h[base + 64 + lane] = v1;
    float pr = v0 * wroot[lane] + v1 * wroot[64 + lane];
    float pl = v0 * wrel[lane] + v1 * wrel[64 + lane];
#pragma unroll
    for (int m = 32; m; m >>= 1) {
        pr += __shfl_xor(pr, m);
        pl += __shfl_xor(pl, m);
    }
    if (lane == 0) { r_[wave] = pr; rel_[wave] = pl; }
}

// ---------------- scorer aggregation + tanh (wave per node, sorted edges) ----------------
__global__ __launch_bounds__(256) void k_score(const float* __restrict__ r_, const float* __restrict__ rel_,
                                               const int* __restrict__ offs, const int* __restrict__ ssrc,
                                               const float* __restrict__ gcb, float* __restrict__ score) {
    int wave = (blockIdx.x * 256 + threadIdx.x) >> 6;
    int lane = threadIdx.x & 63;
    if (wave >= NN) return;
    int p0 = offs[wave], p1 = offs[wave + 1];
    float s = 0.f;
    for (int p = p0 + lane; p < p1; p += 64) s += rel_[ssrc[p]];
#pragma unroll
    for (int m = 32; m; m >>= 1) s += __shfl_xor(s, m);
    if (lane == 0) score[wave] = tanhf(r_[wave] + s + gcb[0]);
}

// ---------------- per-graph top-K (exact bitonic sort of 2048) + weighted mean pool ----------------
__global__ __launch_bounds__(512) void k_topk(const float* __restrict__ score, const float* __restrict__ h,
                                              float* __restrict__ xbout) {
    __shared__ float sv[2048];
    __shared__ int si[2048];
    __shared__ float red[4][128];
    int g = blockIdx.x, tid = threadIdx.x;
    for (int i = tid; i < 2048; i += 512) {
        sv[i] = (i < NPG) ? score[g * NPG + i] : -2.0f;  // scores in [-1,1]
        si[i] = i;
    }
    __syncthreads();
    for (int k = 2; k <= 2048; k <<= 1) {
        for (int j = k >> 1; j > 0; j >>= 1) {
            for (int t = tid; t < 2048; t += 512) {
                int ixj = t ^ j;
                if (ixj > t) {
                    bool up = ((t & k) == 0);  // descending overall
                    float a = sv[t], b = sv[ixj];
                    bool sw = up ? (a < b) : (a > b);
                    if (sw) {
                        sv[t] = b; sv[ixj] = a;
                        int tmp = si[t]; si[t] = si[ixj]; si[ixj] = tmp;
                    }
                }
            }
            __syncthreads();
        }
    }
    int grp = tid >> 7, c = tid & 127;
    float a = 0.f;
    for (int kk = grp; kk < KK; kk += 4) {
        int node = g * NPG + si[kk];
        a += sv[kk] * h[(size_t)node * CC + c];
    }
    red[grp][c] = a;
    __syncthreads();
    if (tid < 128) {
        float v = (red[0][tid] + red[1][tid] + red[2][tid] + red[3][tid]) * (1.f / KK);
        xbout[g * CC + tid] = v;
    }
}

// ---------------- final MLP ----------------
__global__ __launch_bounds__(128) void k_mlp(const float* __restrict__ xb, const float* __restrict__ W1,
                                             const float* __restrict__ b1, const float* __restrict__ W2,
                                             const float* __restrict__ b2, const float* __restrict__ Wo,
                                             const float* __restrict__ bo, float* __restrict__ out) {
    int g = blockIdx.x, tid = threadIdx.x;
    __shared__ float xc[256], l1[128], l2[64];
    xc[tid] = xb[g * CC + tid];
    xc[128 + tid] = xb[BB * CC + g * CC + tid];
    __syncthreads();
    float s = b1[tid];
    for (int i = 0; i < 256; i++) s += xc[i] * W1[i * 128 + tid];
    l1[tid] = (s > 0.f) ? s : 0.1f * s;
    __syncthreads();
    if (tid < 64) {
        float s2 = b2[tid];
        for (int i = 0; i < 128; i++) s2 += l1[i] * W2[i * 64 + tid];
        l2[tid] = (s2 > 0.f) ? s2 : 0.1f * s2;
    }
    __syncthreads();
    if (tid < 64) {
        float p = l2[tid] * Wo[tid];
#pragma unroll
        for (int m = 32; m; m >>= 1) p += __shfl_xor(p, m);
        if (tid == 0) out[g] = 1.f / (1.f + __expf(-(p + bo[0])));
    }
}

extern "C" void kernel_launch(void* const* d_in, const int* in_sizes, int n_in,
                              void* d_out, int out_size, void* d_ws, size_t ws_size,
                              hipStream_t stream) {
    (void)in_sizes; (void)n_in; (void)out_size; (void)ws_size;
    const float* Wl   = (const float*)d_in[6];
    const float* bl   = (const float*)d_in[7];
    const float* Wr   = (const float*)d_in[8];
    const float* We   = (const float*)d_in[9];
    const float* att  = (const float*)d_in[10];
    const float* cb   = (const float*)d_in[11];
    const float* gam  = (const float*)d_in[12];
    const float* bet  = (const float*)d_in[13];
    const float* wrel = (const float*)d_in[14];
    const float* wroot= (const float*)d_in[15];
    const float* gcb  = (const float*)d_in[16];
    const float* W1   = (const float*)d_in[17];
    const float* b1   = (const float*)d_in[18];
    const float* W2   = (const float*)d_in[19];
    const float* b2   = (const float*)d_in[20];
    const float* Wo   = (const float*)d_in[21];
    const float* bo   = (const float*)d_in[22];

    float* ws = (float*)d_ws;
    float*  xl    = ws + XL_OFF;
    float*  xr    = ws + XR_OFF;
    float*  hbn   = ws + HBN_OFF;
    int*    ssrc  = (int*)(ws + SSRC_OFF);
    float2* sea   = (float2*)(ws + SEA_OFF);
    int*    cnt   = (int*)(ws + CNT_OFF);
    int*    offs  = (int*)(ws + OFFS_OFF);
    int*    cur   = (int*)(ws + CUR_OFF);
    float*  r_    = ws + R_OFF;
    float*  rel_  = ws + REL_OFF;
    float*  score = ws + SCORE_OFF;
    float*  bnsum = ws + BNSUM_OFF;
    float*  bnsq  = ws + BNSQ_OFF;
    float*  scale = ws + SCALE_OFF;
    float*  shift = ws + SHIFT_OFF;
    float*  meanea= ws + MEANEA_OFF;
    float*  xb    = ws + XB_OFF;

    for (int br = 0; br < 2; br++) {
        const float* x  = (const float*)d_in[br];
        const int*   ei = (const int*)d_in[2 + br];
        const float* ea = (const float*)d_in[4 + br];

        hipMemsetAsync(cnt, 0, NN * sizeof(int), stream);
        hipMemsetAsync(bnsum, 0, 256 * sizeof(float), stream);   // bnsum + bnsq contiguous
        hipMemsetAsync(meanea, 0, 2 * sizeof(float), stream);

        k_eamean<<<256, 256, 0, stream>>>(ea, meanea);
        k_hist<<<EE / 256, 256, 0, stream>>>(ei, cnt);
        k_scan<<<1, 1024, 0, stream>>>(cnt, offs, cur);
        k_scatter<<<EE / 256, 256, 0, stream>>>(ei, ea, cur, ssrc, sea);

        k_gemm<<<dim3(HC / 64, NN / 64), 256, 0, stream>>>(x, Wl, bl, xl);
        k_gemm<<<dim3(HC / 64, NN / 64), 256, 0, stream>>>(x, Wr, nullptr, xr);

        k_gat<<<NN / 4, 256, 0, stream>>>(xl, xr, offs, ssrc, sea, meanea, We, att, cb, hbn);

        k_bnstats<<<512, 256, 0, stream>>>(hbn, bnsum, bnsq);
        k_bnfinal<<<1, 128, 0, stream>>>(bnsum, bnsq, gam, bet, scale, shift);
        k_bnapply<<<NN / 4, 256, 0, stream>>>(hbn, scale, shift, wroot, wrel, r_, rel_);
        k_score<<<NN / 4, 256, 0, stream>>>(r_, rel_, offs, ssrc, gcb, score);
        k_topk<<<BB, 512, 0, stream>>>(score, hbn, xb + br * BB * CC);
    }
    k_mlp<<<BB, 128, 0, stream>>>(xb, W1, b1, W2, b2, Wo, bo, (float*)d_out);
}

// Round 2
// 1712.780 us; speedup vs baseline: 1.7518x; 1.7518x over previous
//
#include <hip/hip_runtime.h>
#include <hip/hip_bf16.h>
#include <math.h>

#define NN 32000        // total nodes
#define EE 640000       // edges
#define CC 128          // hidden
#define HC 384          // H*C
#define FIN 1038
#define KP 1056         // FIN padded to multiple of 32
#define KT 33           // KP/32
#define BB 16           // graphs
#define NPG 2000
#define KK 400

// ---------------- workspace layout (float elements) ----------------
#define XL_OFF     0u
#define XR_OFF     12288000u
#define HBN_OFF    24576000u
#define SSRC_OFF   28672000u
#define SEA_OFF    29312000u
#define CNT_OFF    30592000u
#define OFFS_OFF   30624000u
#define CUR_OFF    30656064u
#define R_OFF      30688064u
#define REL_OFF    30720064u
#define SCORE_OFF  30752064u
#define BNSUM_OFF  30784064u
#define BNSQ_OFF   30784192u
#define SCALE_OFF  30784320u
#define SHIFT_OFF  30784448u
#define MEANEA_OFF 30784576u
#define XB_OFF     30784640u
#define AH_OFF     30788736u   // 32000*1056 bf16 = 16,896,000 floats
#define AL_OFF     47684736u
#define WTH_OFF    64580736u   // 768*1056 bf16 = 405,504 floats
#define WTL_OFF    64986240u

typedef __attribute__((ext_vector_type(8))) short bf16x8;
typedef __attribute__((ext_vector_type(4))) float f32x4;
typedef __attribute__((ext_vector_type(8))) unsigned short us8;

typedef const __attribute__((address_space(1))) unsigned int* gp1_t;
typedef __attribute__((address_space(3))) unsigned int* lp3_t;
__device__ __forceinline__ void gl_lds16(const void* g, void* l) {
    __builtin_amdgcn_global_load_lds((gp1_t)g, (lp3_t)l, 16, 0, 0);
}

// ---------------- edge-attr mean reduction ----------------
__global__ __launch_bounds__(256) void k_eamean(const float* __restrict__ ea, float* __restrict__ meanea) {
    int tid = threadIdx.x;
    float s0 = 0.f, s1 = 0.f;
    for (int e = blockIdx.x * 256 + tid; e < EE; e += 256 * 256) {
        float2 t = ((const float2*)ea)[e];
        s0 += t.x; s1 += t.y;
    }
    __shared__ float r0[256], r1[256];
    r0[tid] = s0; r1[tid] = s1; __syncthreads();
    for (int st = 128; st; st >>= 1) {
        if (tid < st) { r0[tid] += r0[tid + st]; r1[tid] += r1[tid + st]; }
        __syncthreads();
    }
    if (tid == 0) { atomicAdd(&meanea[0], r0[0]); atomicAdd(&meanea[1], r1[0]); }
}

// ---------------- histogram of dst ----------------
__global__ __launch_bounds__(256) void k_hist(const int* __restrict__ ei, int* __restrict__ cnt) {
    int e = blockIdx.x * 256 + threadIdx.x;
    if (e < EE) atomicAdd(&cnt[ei[EE + e]], 1);
}

// ---------------- exclusive scan over 32000 counters ----------------
__global__ __launch_bounds__(1024) void k_scan(const int* __restrict__ cnt, int* __restrict__ offs, int* __restrict__ cur) {
    __shared__ int sb[1024];
    int tid = threadIdx.x;
    int base = tid * 32;
    int s = 0;
    for (int i = 0; i < 32; i++) { int idx = base + i; s += (idx < NN) ? cnt[idx] : 0; }
    sb[tid] = s; __syncthreads();
    for (int off = 1; off < 1024; off <<= 1) {
        int v = (tid >= off) ? sb[tid - off] : 0;
        __syncthreads();
        sb[tid] += v;
        __syncthreads();
    }
    int run = sb[tid] - s;  // exclusive prefix
    for (int i = 0; i < 32; i++) {
        int idx = base + i;
        if (idx < NN) { int c = cnt[idx]; offs[idx] = run; cur[idx] = run; run += c; }
    }
    if (tid == 1023) offs[NN] = run;
}

// ---------------- scatter edges sorted by dst ----------------
__global__ __launch_bounds__(256) void k_scatter(const int* __restrict__ ei, const float* __restrict__ ea,
                                                 int* __restrict__ cur, int* __restrict__ ssrc, float2* __restrict__ sea) {
    int e = blockIdx.x * 256 + threadIdx.x;
    if (e < EE) {
        int d = ei[EE + e];
        int p = atomicAdd(&cur[d], 1);
        ssrc[p] = ei[e];
        sea[p] = ((const float2*)ea)[e];
    }
}

// ---------------- fp32 -> split bf16 (hi + lo), pad K to 1056 ----------------
__global__ __launch_bounds__(256) void k_cvtA(const float* __restrict__ x,
                                              unsigned short* __restrict__ Ah, unsigned short* __restrict__ Al) {
    int idx = blockIdx.x * 256 + threadIdx.x;
    if (idx >= NN * (KP / 8)) return;
    int row = idx / (KP / 8);
    int seg = idx - row * (KP / 8);
    int c0 = seg * 8;
    us8 h8, l8;
#pragma unroll
    for (int j = 0; j < 8; ++j) {
        int c = c0 + j;
        float v = (c < FIN) ? x[(size_t)row * FIN + c] : 0.f;
        unsigned b = __float_as_uint(v);
        unsigned hb = b & 0xffff0000u;
        float res = v - __uint_as_float(hb);
        h8[j] = (unsigned short)(hb >> 16);
        l8[j] = (unsigned short)(__float_as_uint(res) >> 16);
    }
    *(us8*)&Ah[(size_t)row * KP + c0] = h8;
    *(us8*)&Al[(size_t)row * KP + c0] = l8;
}

// ---------------- weights: transpose to N-major [768][1056], split bf16 ----------------
__global__ __launch_bounds__(256) void k_cvtW(const float* __restrict__ Wl_, const float* __restrict__ Wr_,
                                              unsigned short* __restrict__ Bh, unsigned short* __restrict__ Bl) {
    int idx = blockIdx.x * 256 + threadIdx.x;
    if (idx >= 768 * (KP / 8)) return;
    int n = idx / (KP / 8);
    int seg = idx - n * (KP / 8);
    int c0 = seg * 8;
    const float* W = (n < HC) ? Wl_ : Wr_;
    int nc = (n < HC) ? n : n - HC;
    us8 h8, l8;
#pragma unroll
    for (int j = 0; j < 8; ++j) {
        int k = c0 + j;
        float v = (k < FIN) ? W[(size_t)k * HC + nc] : 0.f;
        unsigned b = __float_as_uint(v);
        unsigned hb = b & 0xffff0000u;
        float res = v - __uint_as_float(hb);
        h8[j] = (unsigned short)(hb >> 16);
        l8[j] = (unsigned short)(__float_as_uint(res) >> 16);
    }
    *(us8*)&Bh[(size_t)n * KP + c0] = h8;
    *(us8*)&Bl[(size_t)n * KP + c0] = l8;
}

// ---------------- MFMA GEMM: C[32000,768] = A[32000,1056] @ Wt^T, 3-term bf16 split ----------------
// C = Ah*Bh + Ah*Bl + Al*Bh  (error ~2^-16). n<384 -> xl (+bias bl), else -> xr.
__global__ __launch_bounds__(256) void k_gemm2(const unsigned short* __restrict__ Ah,
                                               const unsigned short* __restrict__ Al,
                                               const unsigned short* __restrict__ Bh,
                                               const unsigned short* __restrict__ Bl,
                                               const float* __restrict__ bias,
                                               float* __restrict__ xl, float* __restrict__ xr) {
    __shared__ unsigned short sAh[128 * 32], sAl[128 * 32], sBh[128 * 32], sBl[128 * 32];
    const int tid = threadIdx.x;
    const int wave = tid >> 6, lane = tid & 63;
    const int bm = blockIdx.y * 128, bn = blockIdx.x * 128;
    const int wm = (wave >> 1) * 64, wn = (wave & 1) * 64;
    const int quad = lane >> 4, l15 = lane & 15;

    // staging: per wave, issue i covers rows i*64 + wave*16 + (lane>>2), cols (lane&3)*8..+7
    const int srow = wave * 16 + (lane >> 2);
    const int scol = (lane & 3) * 8;
    const size_t gA0 = (size_t)(bm + srow) * KP + scol;
    const size_t gA1 = (size_t)(bm + 64 + srow) * KP + scol;
    const size_t gB0 = (size_t)(bn + srow) * KP + scol;
    const size_t gB1 = (size_t)(bn + 64 + srow) * KP + scol;
    const int l0 = (wave * 16) * 32 + lane * 8;
    const int l1 = (64 + wave * 16) * 32 + lane * 8;

    f32x4 acc[4][4];
#pragma unroll
    for (int i = 0; i < 4; ++i)
#pragma unroll
        for (int j = 0; j < 4; ++j) {
            f32x4 z = {0.f, 0.f, 0.f, 0.f};
            acc[i][j] = z;
        }

    const int aoff0 = (wm + l15) * 32 + quad * 8;   // + i*512
    const int boff0 = (wn + l15) * 32 + quad * 8;   // + j*512

    for (int kt = 0; kt < KT; ++kt) {
        const int kc = kt * 32;
        gl_lds16(Ah + gA0 + kc, &sAh[l0]);
        gl_lds16(Ah + gA1 + kc, &sAh[l1]);
        gl_lds16(Al + gA0 + kc, &sAl[l0]);
        gl_lds16(Al + gA1 + kc, &sAl[l1]);
        gl_lds16(Bh + gB0 + kc, &sBh[l0]);
        gl_lds16(Bh + gB1 + kc, &sBh[l1]);
        gl_lds16(Bl + gB0 + kc, &sBl[l0]);
        gl_lds16(Bl + gB1 + kc, &sBl[l1]);
        __syncthreads();   // drains vmcnt (global_load_lds) + lds visibility
        bf16x8 ah[4], al[4], bh[4], blo[4];
#pragma unroll
        for (int i = 0; i < 4; ++i) {
            ah[i]  = *(const bf16x8*)&sAh[aoff0 + i * 512];
            al[i]  = *(const bf16x8*)&sAl[aoff0 + i * 512];
            bh[i]  = *(const bf16x8*)&sBh[boff0 + i * 512];
            blo[i] = *(const bf16x8*)&sBl[boff0 + i * 512];
        }
#pragma unroll
        for (int i = 0; i < 4; ++i)
#pragma unroll
            for (int j = 0; j < 4; ++j) {
                acc[i][j] = __builtin_amdgcn_mfma_f32_16x16x32_bf16(ah[i], bh[j],  acc[i][j], 0, 0, 0);
                acc[i][j] = __builtin_amdgcn_mfma_f32_16x16x32_bf16(ah[i], blo[j], acc[i][j], 0, 0, 0);
                acc[i][j] = __builtin_amdgcn_mfma_f32_16x16x32_bf16(al[i], bh[j],  acc[i][j], 0, 0, 0);
            }
        __syncthreads();   // protect LDS before next stage
    }

    // epilogue: C/D layout col=lane&15, row=quad*4+reg
#pragma unroll
    for (int i = 0; i < 4; ++i) {
#pragma unroll
        for (int r = 0; r < 4; ++r) {
            int m = bm + wm + i * 16 + quad * 4 + r;
#pragma unroll
            for (int j = 0; j < 4; ++j) {
                int n = bn + wn + j * 16 + l15;
                float v = acc[i][j][r];
                if (n < HC) xl[(size_t)m * HC + n] = v + bias[n];
                else        xr[(size_t)m * HC + (n - HC)] = v;
            }
        }
    }
}

// ---------------- fused GATv2 per-dst aggregation (one wave per node) ----------------
__global__ __launch_bounds__(256) void k_gat(const float* __restrict__ xl, const float* __restrict__ xr,
                                             const int* __restrict__ offs, const int* __restrict__ ssrc,
                                             const float2* __restrict__ sea, const float* __restrict__ meanea,
                                             const float* __restrict__ We, const float* __restrict__ att,
                                             const float* __restrict__ conv_bias, float* __restrict__ hout) {
    int wave = (blockIdx.x * 256 + threadIdx.x) >> 6;
    int lane = threadIdx.x & 63;
    if (wave >= NN) return;
    float we0[6], we1[6], attv[6], xrv[6];
#pragma unroll
    for (int j = 0; j < 6; j++) {
        int i = j * 64 + lane;
        we0[j] = We[i]; we1[j] = We[HC + i]; attv[j] = att[i];
        xrv[j] = xr[(size_t)wave * HC + i];
    }
    float me0 = meanea[0] * (1.0f / EE), me1 = meanea[1] * (1.0f / EE);
    float acc[6] = {0, 0, 0, 0, 0, 0};
    float den0 = 0, den1 = 0, den2 = 0;
    int p0 = offs[wave], p1 = offs[wave + 1];
    for (int p = p0 - 1; p < p1; ++p) {
        int s; float ea0, ea1;
        if (p < p0) { s = wave; ea0 = me0; ea1 = me1; }   // self loop (fill='mean')
        else { s = ssrc[p]; float2 t = sea[p]; ea0 = t.x; ea1 = t.y; }
        const float* xls = xl + (size_t)s * HC;
        float xv[6], pr0 = 0, pr1 = 0, pr2 = 0;
#pragma unroll
        for (int j = 0; j < 6; j++) {
            float v = xls[j * 64 + lane];
            xv[j] = v;
            float m = v + xrv[j] + ea0 * we0[j] + ea1 * we1[j];
            float t = (m > 0.f) ? m : 0.2f * m;
            float c = t * attv[j];
            if (j < 2) pr0 += c; else if (j < 4) pr1 += c; else pr2 += c;
        }
#pragma unroll
        for (int mask = 32; mask; mask >>= 1) {
            pr0 += __shfl_xor(pr0, mask);
            pr1 += __shfl_xor(pr1, mask);
            pr2 += __shfl_xor(pr2, mask);
        }
        float w0 = __expf(pr0), w1 = __expf(pr1), w2 = __expf(pr2);
        den0 += w0; den1 += w1; den2 += w2;
        acc[0] += w0 * xv[0]; acc[1] += w0 * xv[1];
        acc[2] += w1 * xv[2]; acc[3] += w1 * xv[3];
        acc[4] += w2 * xv[4]; acc[5] += w2 * xv[5];
    }
    float i0 = 1.f / den0, i1 = 1.f / den1, i2 = 1.f / den2;
    float o0 = (acc[0] * i0 + acc[2] * i1 + acc[4] * i2) * (1.f / 3.f) + conv_bias[lane];
    float o1 = (acc[1] * i0 + acc[3] * i1 + acc[5] * i2) * (1.f / 3.f) + conv_bias[64 + lane];
    o0 = (o0 > 0.f) ? o0 : 0.1f * o0;
    o1 = (o1 > 0.f) ? o1 : 0.1f * o1;
    hout[(size_t)wave * CC + lane] = o0;
    hout[(size_t)wave * CC + 64 + lane] = o1;
}

// ---------------- batchnorm stats ----------------
__global__ __launch_bounds__(256) void k_bnstats(const float* __restrict__ h, float* __restrict__ bnsum, float* __restrict__ bnsq) {
    int c = threadIdx.x & 127;
    int row0 = blockIdx.x * 2 + (threadIdx.x >> 7);
    float s = 0.f, ss = 0.f;
    for (int n = row0; n < NN; n += gridDim.x * 2) {
        float v = h[(size_t)n * CC + c];
        s += v; ss += v * v;
    }
    atomicAdd(&bnsum[c], s);
    atomicAdd(&bnsq[c], ss);
}

__global__ __launch_bounds__(128) void k_bnfinal(const float* __restrict__ bnsum, const float* __restrict__ bnsq,
                                                 const float* __restrict__ gamma, const float* __restrict__ beta,
                                                 float* __restrict__ scale, float* __restrict__ shift) {
    int c = threadIdx.x;
    float mu = bnsum[c] * (1.f / NN);
    float var = bnsq[c] * (1.f / NN) - mu * mu;
    float sc = gamma[c] * rsqrtf(var + 1e-5f);
    scale[c] = sc;
    shift[c] = beta[c] - mu * sc;
}

// ---------------- BN apply + scorer dot products (wave per node) ----------------
__global__ __launch_bounds__(256) void k_bnapply(float* __restrict__ h, const float* __restrict__ scale,
                                                 const float* __restrict__ shift, const float* __restrict__ wroot,
                                                 const float* __restrict__ wrel, float* __restrict__ r_, float* __restrict__ rel_) {
    int wave = (blockIdx.x * 256 + threadIdx.x) >> 6;
    int lane = threadIdx.x & 63;
    if (wave >= NN) return;
    size_t base = (size_t)wave * CC;
    float v0 = h[base + lane], v1 = h[base + 64 + lane];
    v0 = v0 * scale[lane] + shift[lane];
    v1 = v1 * scale[64 + lane] + shift[64 + lane];
    h[base + lane] = v0;
    h[base + 64 + lane] = v1;
    float pr = v0 * wroot[lane] + v1 * wroot[64 + lane];
    float pl = v0 * wrel[lane] + v1 * wrel[64 + lane];
#pragma unroll
    for (int m = 32; m; m >>= 1) {
        pr += __shfl_xor(pr, m);
        pl += __shfl_xor(pl, m);
    }
    if (lane == 0) { r_[wave] = pr; rel_[wave] = pl; }
}

// ---------------- scorer aggregation + tanh (wave per node, sorted edges) ----------------
__global__ __launch_bounds__(256) void k_score(const float* __restrict__ r_, const float* __restrict__ rel_,
                                               const int* __restrict__ offs, const int* __restrict__ ssrc,
                                               const float* __restrict__ gcb, float* __restrict__ score) {
    int wave = (blockIdx.x * 256 + threadIdx.x) >> 6;
    int lane = threadIdx.x & 63;
    if (wave >= NN) return;
    int p0 = offs[wave], p1 = offs[wave + 1];
    float s = 0.f;
    for (int p = p0 + lane; p < p1; p += 64) s += rel_[ssrc[p]];
#pragma unroll
    for (int m = 32; m; m >>= 1) s += __shfl_xor(s, m);
    if (lane == 0) score[wave] = tanhf(r_[wave] + s + gcb[0]);
}

// ---------------- per-graph top-K (exact bitonic sort of 2048) + weighted mean pool ----------------
__global__ __launch_bounds__(512) void k_topk(const float* __restrict__ score, const float* __restrict__ h,
                                              float* __restrict__ xbout) {
    __shared__ float sv[2048];
    __shared__ int si[2048];
    __shared__ float red[4][128];
    int g = blockIdx.x, tid = threadIdx.x;
    for (int i = tid; i < 2048; i += 512) {
        sv[i] = (i < NPG) ? score[g * NPG + i] : -2.0f;  // scores in [-1,1]
        si[i] = i;
    }
    __syncthreads();
    for (int k = 2; k <= 2048; k <<= 1) {
        for (int j = k >> 1; j > 0; j >>= 1) {
            for (int t = tid; t < 2048; t += 512) {
                int ixj = t ^ j;
                if (ixj > t) {
                    bool up = ((t & k) == 0);  // descending overall
                    float a = sv[t], b = sv[ixj];
                    bool sw = up ? (a < b) : (a > b);
                    if (sw) {
                        sv[t] = b; sv[ixj] = a;
                        int tmp = si[t]; si[t] = si[ixj]; si[ixj] = tmp;
                    }
                }
            }
            __syncthreads();
        }
    }
    int grp = tid >> 7, c = tid & 127;
    float a = 0.f;
    for (int kk = grp; kk < KK; kk += 4) {
        int node = g * NPG + si[kk];
        a += sv[kk] * h[(size_t)node * CC + c];
    }
    red[grp][c] = a;
    __syncthreads();
    if (tid < 128) {
        float v = (red[0][tid] + red[1][tid] + red[2][tid] + red[3][tid]) * (1.f / KK);
        xbout[g * CC + tid] = v;
    }
}

// ---------------- final MLP ----------------
__global__ __launch_bounds__(128) void k_mlp(const float* __restrict__ xb, const float* __restrict__ W1,
                                             const float* __restrict__ b1, const float* __restrict__ W2,
                                             const float* __restrict__ b2, const float* __restrict__ Wo,
                                             const float* __restrict__ bo, float* __restrict__ out) {
    int g = blockIdx.x, tid = threadIdx.x;
    __shared__ float xc[256], l1[128], l2[64];
    xc[tid] = xb[g * CC + tid];
    xc[128 + tid] = xb[BB * CC + g * CC + tid];
    __syncthreads();
    float s = b1[tid];
    for (int i = 0; i < 256; i++) s += xc[i] * W1[i * 128 + tid];
    l1[tid] = (s > 0.f) ? s : 0.1f * s;
    __syncthreads();
    if (tid < 64) {
        float s2 = b2[tid];
        for (int i = 0; i < 128; i++) s2 += l1[i] * W2[i * 64 + tid];
        l2[tid] = (s2 > 0.f) ? s2 : 0.1f * s2;
    }
    __syncthreads();
    if (tid < 64) {
        float p = l2[tid] * Wo[tid];
#pragma unroll
        for (int m = 32; m; m >>= 1) p += __shfl_xor(p, m);
        if (tid == 0) out[g] = 1.f / (1.f + __expf(-(p + bo[0])));
    }
}

extern "C" void kernel_launch(void* const* d_in, const int* in_sizes, int n_in,
                              void* d_out, int out_size, void* d_ws, size_t ws_size,
                              hipStream_t stream) {
    (void)in_sizes; (void)n_in; (void)out_size; (void)ws_size;
    const float* Wl   = (const float*)d_in[6];
    const float* bl   = (const float*)d_in[7];
    const float* Wr   = (const float*)d_in[8];
    const float* We   = (const float*)d_in[9];
    const float* att  = (const float*)d_in[10];
    const float* cb   = (const float*)d_in[11];
    const float* gam  = (const float*)d_in[12];
    const float* bet  = (const float*)d_in[13];
    const float* wrel = (const float*)d_in[14];
    const float* wroot= (const float*)d_in[15];
    const float* gcb  = (const float*)d_in[16];
    const float* W1   = (const float*)d_in[17];
    const float* b1   = (const float*)d_in[18];
    const float* W2   = (const float*)d_in[19];
    const float* b2   = (const float*)d_in[20];
    const float* Wo   = (const float*)d_in[21];
    const float* bo   = (const float*)d_in[22];

    float* ws = (float*)d_ws;
    float*  xl    = ws + XL_OFF;
    float*  xr    = ws + XR_OFF;
    float*  hbn   = ws + HBN_OFF;
    int*    ssrc  = (int*)(ws + SSRC_OFF);
    float2* sea   = (float2*)(ws + SEA_OFF);
    int*    cnt   = (int*)(ws + CNT_OFF);
    int*    offs  = (int*)(ws + OFFS_OFF);
    int*    cur   = (int*)(ws + CUR_OFF);
    float*  r_    = ws + R_OFF;
    float*  rel_  = ws + REL_OFF;
    float*  score = ws + SCORE_OFF;
    float*  bnsum = ws + BNSUM_OFF;
    float*  bnsq  = ws + BNSQ_OFF;
    float*  scale = ws + SCALE_OFF;
    float*  shift = ws + SHIFT_OFF;
    float*  meanea= ws + MEANEA_OFF;
    float*  xb    = ws + XB_OFF;
    unsigned short* Ah  = (unsigned short*)(ws + AH_OFF);
    unsigned short* Al2 = (unsigned short*)(ws + AL_OFF);
    unsigned short* Wth = (unsigned short*)(ws + WTH_OFF);
    unsigned short* Wtl = (unsigned short*)(ws + WTL_OFF);

    k_cvtW<<<(768 * (KP / 8) + 255) / 256, 256, 0, stream>>>(Wl, Wr, Wth, Wtl);

    for (int br = 0; br < 2; br++) {
        const float* x  = (const float*)d_in[br];
        const int*   ei = (const int*)d_in[2 + br];
        const float* ea = (const float*)d_in[4 + br];

        hipMemsetAsync(cnt, 0, NN * sizeof(int), stream);
        hipMemsetAsync(bnsum, 0, 256 * sizeof(float), stream);   // bnsum + bnsq contiguous
        hipMemsetAsync(meanea, 0, 2 * sizeof(float), stream);

        k_eamean<<<256, 256, 0, stream>>>(ea, meanea);
        k_hist<<<EE / 256, 256, 0, stream>>>(ei, cnt);
        k_scan<<<1, 1024, 0, stream>>>(cnt, offs, cur);
        k_scatter<<<EE / 256, 256, 0, stream>>>(ei, ea, cur, ssrc, sea);

        k_cvtA<<<(NN * (KP / 8) + 255) / 256, 256, 0, stream>>>(x, Ah, Al2);
        k_gemm2<<<dim3(768 / 128, NN / 128), 256, 0, stream>>>(Ah, Al2, Wth, Wtl, bl, xl, xr);

        k_gat<<<NN / 4, 256, 0, stream>>>(xl, xr, offs, ssrc, sea, meanea, We, att, cb, hbn);

        k_bnstats<<<512, 256, 0, stream>>>(hbn, bnsum, bnsq);
        k_bnfinal<<<1, 128, 0, stream>>>(bnsum, bnsq, gam, bet, scale, shift);
        k_bnapply<<<NN / 4, 256, 0, stream>>>(hbn, scale, shift, wroot, wrel, r_, rel_);
        k_score<<<NN / 4, 256, 0, stream>>>(r_, rel_, offs, ssrc, gcb, score);
        k_topk<<<BB, 512, 0, stream>>>(score, hbn, xb + br * BB * CC);
    }
    k_mlp<<<BB, 128, 0, stream>>>(xb, W1, b1, W2, b2, Wo, bo, (float*)d_out);
}

// Round 3
// 1697.797 us; speedup vs baseline: 1.7673x; 1.0088x over previous
//
#include <hip/hip_runtime.h>
#include <hip/hip_bf16.h>
#include <math.h>

#define NN 32000        // total nodes
#define EE 640000       // edges
#define CC 128          // hidden
#define HC 384          // H*C
#define FIN 1038
#define KP 1056         // FIN padded to multiple of 32
#define KT 33           // KP/32
#define BB 16           // graphs
#define NPG 2000
#define KK 400

// ---------------- workspace layout (float elements) ----------------
#define XL_OFF     0u
#define XR_OFF     12288000u
#define HBN_OFF    24576000u
#define SSRC_OFF   28672000u
#define SEA_OFF    29312000u
#define CNT_OFF    30592000u   // zero-block start: cnt(32000) + bnsum(128) + bnsq(128) + meanea(2)
#define BNSUM_OFF  30624000u
#define BNSQ_OFF   30624128u
#define MEANEA_OFF 30624256u
#define ZERO_BYTES ((30624258u - 30592000u) * 4u)
#define OFFS_OFF   30624320u
#define CUR_OFF    30656384u
#define R_OFF      30688384u
#define REL_OFF    30720384u
#define SCORE_OFF  30752384u
#define XB_OFF     30784384u
#define AH_OFF     30788480u   // 32000*1056 bf16 = 16,896,000 floats
#define AL_OFF     47684480u
#define WTH_OFF    64580480u   // 768*1056 bf16 = 405,504 floats
#define WTL_OFF    64985984u

typedef __attribute__((ext_vector_type(8))) short bf16x8;
typedef __attribute__((ext_vector_type(4))) float f32x4;
typedef __attribute__((ext_vector_type(8))) unsigned short us8;

typedef const __attribute__((address_space(1))) unsigned int* gp1_t;
typedef __attribute__((address_space(3))) unsigned int* lp3_t;
__device__ __forceinline__ void gl_lds16(const void* g, void* l) {
    __builtin_amdgcn_global_load_lds((gp1_t)g, (lp3_t)l, 16, 0, 0);
}

// ---------------- fused: dst histogram + edge-attr mean ----------------
__global__ __launch_bounds__(256) void k_prep(const int* __restrict__ ei, const float* __restrict__ ea,
                                              int* __restrict__ cnt, float* __restrict__ meanea) {
    int tid = threadIdx.x;
    int e = blockIdx.x * 256 + tid;
    float s0 = 0.f, s1 = 0.f;
    if (e < EE) {
        atomicAdd(&cnt[ei[EE + e]], 1);
        float2 t = ((const float2*)ea)[e];
        s0 = t.x; s1 = t.y;
    }
    __shared__ float r0[256], r1[256];
    r0[tid] = s0; r1[tid] = s1; __syncthreads();
    for (int st = 128; st; st >>= 1) {
        if (tid < st) { r0[tid] += r0[tid + st]; r1[tid] += r1[tid + st]; }
        __syncthreads();
    }
    if (tid == 0) { atomicAdd(&meanea[0], r0[0]); atomicAdd(&meanea[1], r1[0]); }
}

// ---------------- exclusive scan over 32000 counters ----------------
__global__ __launch_bounds__(1024) void k_scan(const int* __restrict__ cnt, int* __restrict__ offs, int* __restrict__ cur) {
    __shared__ int sb[1024];
    int tid = threadIdx.x;
    int base = tid * 32;
    int s = 0;
    for (int i = 0; i < 32; i++) { int idx = base + i; s += (idx < NN) ? cnt[idx] : 0; }
    sb[tid] = s; __syncthreads();
    for (int off = 1; off < 1024; off <<= 1) {
        int v = (tid >= off) ? sb[tid - off] : 0;
        __syncthreads();
        sb[tid] += v;
        __syncthreads();
    }
    int run = sb[tid] - s;  // exclusive prefix
    for (int i = 0; i < 32; i++) {
        int idx = base + i;
        if (idx < NN) { int c = cnt[idx]; offs[idx] = run; cur[idx] = run; run += c; }
    }
    if (tid == 1023) offs[NN] = run;
}

// ---------------- scatter edges sorted by dst ----------------
__global__ __launch_bounds__(256) void k_scatter(const int* __restrict__ ei, const float* __restrict__ ea,
                                                 int* __restrict__ cur, int* __restrict__ ssrc, float2* __restrict__ sea) {
    int e = blockIdx.x * 256 + threadIdx.x;
    if (e < EE) {
        int d = ei[EE + e];
        int p = atomicAdd(&cur[d], 1);
        ssrc[p] = ei[e];
        sea[p] = ((const float2*)ea)[e];
    }
}

// ---------------- fp32 -> split bf16 (hi + lo), pad K to 1056 ----------------
__global__ __launch_bounds__(256) void k_cvtA(const float* __restrict__ x,
                                              unsigned short* __restrict__ Ah, unsigned short* __restrict__ Al) {
    int idx = blockIdx.x * 256 + threadIdx.x;
    if (idx >= NN * (KP / 8)) return;
    int row = idx / (KP / 8);
    int seg = idx - row * (KP / 8);
    int c0 = seg * 8;
    us8 h8, l8;
#pragma unroll
    for (int j = 0; j < 8; ++j) {
        int c = c0 + j;
        float v = (c < FIN) ? x[(size_t)row * FIN + c] : 0.f;
        unsigned b = __float_as_uint(v);
        unsigned hb = b & 0xffff0000u;
        float res = v - __uint_as_float(hb);
        h8[j] = (unsigned short)(hb >> 16);
        l8[j] = (unsigned short)(__float_as_uint(res) >> 16);
    }
    *(us8*)&Ah[(size_t)row * KP + c0] = h8;
    *(us8*)&Al[(size_t)row * KP + c0] = l8;
}

// ---------------- weights: transpose to N-major [768][1056], split bf16 ----------------
__global__ __launch_bounds__(256) void k_cvtW(const float* __restrict__ Wl_, const float* __restrict__ Wr_,
                                              unsigned short* __restrict__ Bh, unsigned short* __restrict__ Bl) {
    int idx = blockIdx.x * 256 + threadIdx.x;
    if (idx >= 768 * (KP / 8)) return;
    int n = idx / (KP / 8);
    int seg = idx - n * (KP / 8);
    int c0 = seg * 8;
    const float* W = (n < HC) ? Wl_ : Wr_;
    int nc = (n < HC) ? n : n - HC;
    us8 h8, l8;
#pragma unroll
    for (int j = 0; j < 8; ++j) {
        int k = c0 + j;
        float v = (k < FIN) ? W[(size_t)k * HC + nc] : 0.f;
        unsigned b = __float_as_uint(v);
        unsigned hb = b & 0xffff0000u;
        float res = v - __uint_as_float(hb);
        h8[j] = (unsigned short)(hb >> 16);
        l8[j] = (unsigned short)(__float_as_uint(res) >> 16);
    }
    *(us8*)&Bh[(size_t)n * KP + c0] = h8;
    *(us8*)&Bl[(size_t)n * KP + c0] = l8;
}

// ---------------- MFMA GEMM: C[32000,768] = A[32000,1056] @ Wt^T, 3-term bf16 split ----------------
// C = Ah*Bh + Ah*Bl + Al*Bh  (error ~2^-16). N-tiles 0-2 -> xl (+bias), 3-5 -> xr.
// Grid: 1504 1D blocks; XCD-aware remap so all 6 N-tiles of an M-tile land on one XCD
// (A-tile 540 KB stays in that XCD's 4 MB L2 across its 6 uses).
__global__ __launch_bounds__(256) void k_gemm2(const unsigned short* __restrict__ Ah,
                                               const unsigned short* __restrict__ Al,
                                               const unsigned short* __restrict__ Bh,
                                               const unsigned short* __restrict__ Bl,
                                               const float* __restrict__ bias,
                                               float* __restrict__ xl, float* __restrict__ xr) {
    __shared__ unsigned short sAh[128 * 32], sAl[128 * 32], sBh[128 * 32], sBl[128 * 32];
    const int bid = blockIdx.x;
    const int xcd = bid & 7, slot = bid >> 3;
    const int t = xcd * 188 + slot;          // 1504/8 = 188 slots per XCD
    if (t >= 1500) return;
    const int mt = t / 6, nt = t - mt * 6;
    const int bm = mt * 128, bn = nt * 128;

    const int tid = threadIdx.x;
    const int wave = tid >> 6, lane = tid & 63;
    const int wm = (wave >> 1) * 64, wn = (wave & 1) * 64;
    const int quad = lane >> 4, l15 = lane & 15;

    // staging: per wave, issue i covers rows i*64 + wave*16 + (lane>>2), cols (lane&3)*8..+7
    const int srow = wave * 16 + (lane >> 2);
    const int scol = (lane & 3) * 8;
    const size_t gA0 = (size_t)(bm + srow) * KP + scol;
    const size_t gA1 = (size_t)(bm + 64 + srow) * KP + scol;
    const size_t gB0 = (size_t)(bn + srow) * KP + scol;
    const size_t gB1 = (size_t)(bn + 64 + srow) * KP + scol;
    const int l0 = (wave * 16) * 32 + lane * 8;
    const int l1 = (64 + wave * 16) * 32 + lane * 8;

    f32x4 acc[4][4];
#pragma unroll
    for (int i = 0; i < 4; ++i)
#pragma unroll
        for (int j = 0; j < 4; ++j) {
            f32x4 z = {0.f, 0.f, 0.f, 0.f};
            acc[i][j] = z;
        }

    const int aoff0 = (wm + l15) * 32 + quad * 8;   // + i*512
    const int boff0 = (wn + l15) * 32 + quad * 8;   // + j*512

    for (int kt = 0; kt < KT; ++kt) {
        const int kc = kt * 32;
        gl_lds16(Ah + gA0 + kc, &sAh[l0]);
        gl_lds16(Ah + gA1 + kc, &sAh[l1]);
        gl_lds16(Al + gA0 + kc, &sAl[l0]);
        gl_lds16(Al + gA1 + kc, &sAl[l1]);
        gl_lds16(Bh + gB0 + kc, &sBh[l0]);
        gl_lds16(Bh + gB1 + kc, &sBh[l1]);
        gl_lds16(Bl + gB0 + kc, &sBl[l0]);
        gl_lds16(Bl + gB1 + kc, &sBl[l1]);
        __syncthreads();   // drains vmcnt (global_load_lds) + lds visibility
        bf16x8 ah[4], al[4], bh[4], blo[4];
#pragma unroll
        for (int i = 0; i < 4; ++i) {
            ah[i]  = *(const bf16x8*)&sAh[aoff0 + i * 512];
            al[i]  = *(const bf16x8*)&sAl[aoff0 + i * 512];
            bh[i]  = *(const bf16x8*)&sBh[boff0 + i * 512];
            blo[i] = *(const bf16x8*)&sBl[boff0 + i * 512];
        }
#pragma unroll
        for (int i = 0; i < 4; ++i)
#pragma unroll
            for (int j = 0; j < 4; ++j) {
                acc[i][j] = __builtin_amdgcn_mfma_f32_16x16x32_bf16(ah[i], bh[j],  acc[i][j], 0, 0, 0);
                acc[i][j] = __builtin_amdgcn_mfma_f32_16x16x32_bf16(ah[i], blo[j], acc[i][j], 0, 0, 0);
                acc[i][j] = __builtin_amdgcn_mfma_f32_16x16x32_bf16(al[i], bh[j],  acc[i][j], 0, 0, 0);
            }
        __syncthreads();   // protect LDS before next stage
    }

    // epilogue: C/D layout col=lane&15, row=quad*4+reg. Block is purely xl or purely xr.
    const bool isL = (nt < 3);
    float* outp = isL ? xl : xr;
    const int nbase = isL ? bn : (bn - HC);
#pragma unroll
    for (int j = 0; j < 4; ++j) {
        const int ncol = wn + j * 16 + l15;
        const float bj = isL ? bias[bn + ncol] : 0.f;
#pragma unroll
        for (int i = 0; i < 4; ++i) {
#pragma unroll
            for (int r = 0; r < 4; ++r) {
                int m = bm + wm + i * 16 + quad * 4 + r;
                outp[(size_t)m * HC + nbase + ncol] = acc[i][j][r] + bj;
            }
        }
    }
}

// ---------------- fused GATv2 per-dst aggregation (one wave per node, prefetch-pipelined) ----------------
__global__ __launch_bounds__(256) void k_gat(const float* __restrict__ xl, const float* __restrict__ xr,
                                             const int* __restrict__ offs, const int* __restrict__ ssrc,
                                             const float2* __restrict__ sea, const float* __restrict__ meanea,
                                             const float* __restrict__ We, const float* __restrict__ att,
                                             const float* __restrict__ conv_bias, float* __restrict__ hout) {
    int wave = (blockIdx.x * 256 + threadIdx.x) >> 6;
    int lane = threadIdx.x & 63;
    if (wave >= NN) return;
    float we0[6], we1[6], attv[6], xrv[6];
#pragma unroll
    for (int j = 0; j < 6; j++) {
        int i = j * 64 + lane;
        we0[j] = We[i]; we1[j] = We[HC + i]; attv[j] = att[i];
        xrv[j] = xr[(size_t)wave * HC + i];
    }
    float me0 = meanea[0] * (1.0f / EE), me1 = meanea[1] * (1.0f / EE);
    float acc[6] = {0, 0, 0, 0, 0, 0};
    float den0 = 0, den1 = 0, den2 = 0;
    int p0 = offs[wave], p1 = offs[wave + 1];

    // prime pipeline with the self loop (p = p0-1, fill='mean')
    float ea0 = me0, ea1 = me1;
    float xv[6];
    {
        const float* xp = xl + (size_t)wave * HC;
#pragma unroll
        for (int j = 0; j < 6; j++) xv[j] = xp[j * 64 + lane];
    }
    for (int p = p0 - 1; p < p1; ++p) {
        // prefetch next edge's gather before the reduce chain (hides L3 latency)
        float xn[6], na0 = 0.f, na1 = 0.f;
        if (p + 1 < p1) {
            int sn = ssrc[p + 1];
            float2 t = sea[p + 1];
            na0 = t.x; na1 = t.y;
            const float* xq = xl + (size_t)sn * HC;
#pragma unroll
            for (int j = 0; j < 6; j++) xn[j] = xq[j * 64 + lane];
        } else {
#pragma unroll
            for (int j = 0; j < 6; j++) xn[j] = 0.f;
        }
        float pr0 = 0, pr1 = 0, pr2 = 0;
#pragma unroll
        for (int j = 0; j < 6; j++) {
            float m = xv[j] + xrv[j] + ea0 * we0[j] + ea1 * we1[j];
            float t = (m > 0.f) ? m : 0.2f * m;
            float c = t * attv[j];
            if (j < 2) pr0 += c; else if (j < 4) pr1 += c; else pr2 += c;
        }
#pragma unroll
        for (int mask = 32; mask; mask >>= 1) {
            pr0 += __shfl_xor(pr0, mask);
            pr1 += __shfl_xor(pr1, mask);
            pr2 += __shfl_xor(pr2, mask);
        }
        float w0 = __expf(pr0), w1 = __expf(pr1), w2 = __expf(pr2);
        den0 += w0; den1 += w1; den2 += w2;
        acc[0] += w0 * xv[0]; acc[1] += w0 * xv[1];
        acc[2] += w1 * xv[2]; acc[3] += w1 * xv[3];
        acc[4] += w2 * xv[4]; acc[5] += w2 * xv[5];
#pragma unroll
        for (int j = 0; j < 6; j++) xv[j] = xn[j];
        ea0 = na0; ea1 = na1;
    }
    float i0 = 1.f / den0, i1 = 1.f / den1, i2 = 1.f / den2;
    float o0 = (acc[0] * i0 + acc[2] * i1 + acc[4] * i2) * (1.f / 3.f) + conv_bias[lane];
    float o1 = (acc[1] * i0 + acc[3] * i1 + acc[5] * i2) * (1.f / 3.f) + conv_bias[64 + lane];
    o0 = (o0 > 0.f) ? o0 : 0.1f * o0;
    o1 = (o1 > 0.f) ? o1 : 0.1f * o1;
    hout[(size_t)wave * CC + lane] = o0;
    hout[(size_t)wave * CC + 64 + lane] = o1;
}

// ---------------- batchnorm stats ----------------
__global__ __launch_bounds__(256) void k_bnstats(const float* __restrict__ h, float* __restrict__ bnsum, float* __restrict__ bnsq) {
    int c = threadIdx.x & 127;
    int row0 = blockIdx.x * 2 + (threadIdx.x >> 7);
    float s = 0.f, ss = 0.f;
    for (int n = row0; n < NN; n += gridDim.x * 2) {
        float v = h[(size_t)n * CC + c];
        s += v; ss += v * v;
    }
    atomicAdd(&bnsum[c], s);
    atomicAdd(&bnsq[c], ss);
}

// ---------------- BN apply (folds bnfinal) + scorer dot products (wave per node) ----------------
__global__ __launch_bounds__(256) void k_bnapply(float* __restrict__ h, const float* __restrict__ bnsum,
                                                 const float* __restrict__ bnsq,
                                                 const float* __restrict__ gamma, const float* __restrict__ beta,
                                                 const float* __restrict__ wroot,
                                                 const float* __restrict__ wrel, float* __restrict__ r_, float* __restrict__ rel_) {
    int wave = (blockIdx.x * 256 + threadIdx.x) >> 6;
    int lane = threadIdx.x & 63;
    if (wave >= NN) return;
    // per-lane scale/shift for channels lane and lane+64 (cheap: 2x ~6 VALU)
    float mu0 = bnsum[lane] * (1.f / NN);
    float var0 = bnsq[lane] * (1.f / NN) - mu0 * mu0;
    float sc0 = gamma[lane] * rsqrtf(var0 + 1e-5f);
    float sh0 = beta[lane] - mu0 * sc0;
    float mu1 = bnsum[64 + lane] * (1.f / NN);
    float var1 = bnsq[64 + lane] * (1.f / NN) - mu1 * mu1;
    float sc1 = gamma[64 + lane] * rsqrtf(var1 + 1e-5f);
    float sh1 = beta[64 + lane] - mu1 * sc1;

    size_t base = (size_t)wave * CC;
    float v0 = h[base + lane], v1 = h[base + 64 + lane];
    v0 = v0 * sc0 + sh0;
    v1 = v1 * sc1 + sh1;
    h[base + lane] = v0;
    h[base + 64 + lane] = v1;
    float pr = v0 * wroot[lane] + v1 * wroot[64 + lane];
    float pl = v0 * wrel[lane] + v1 * wrel[64 + lane];
#pragma unroll
    for (int m = 32; m; m >>= 1) {
        pr += __shfl_xor(pr, m);
        pl += __shfl_xor(pl, m);
    }
    if (lane == 0) { r_[wave] = pr; rel_[wave] = pl; }
}

// ---------------- scorer aggregation + tanh (wave per node, sorted edges) ----------------
__global__ __launch_bounds__(256) void k_score(const float* __restrict__ r_, const float* __restrict__ rel_,
                                               const int* __restrict__ offs, const int* __restrict__ ssrc,
                                               const float* __restrict__ gcb, float* __restrict__ score) {
    int wave = (blockIdx.x * 256 + threadIdx.x) >> 6;
    int lane = threadIdx.x & 63;
    if (wave >= NN) return;
    int p0 = offs[wave], p1 = offs[wave + 1];
    float s = 0.f;
    for (int p = p0 + lane; p < p1; p += 64) s += rel_[ssrc[p]];
#pragma unroll
    for (int m = 32; m; m >>= 1) s += __shfl_xor(s, m);
    if (lane == 0) score[wave] = tanhf(r_[wave] + s + gcb[0]);
}

// ---------------- per-graph top-K (exact bitonic sort of 2048) + weighted mean pool ----------------
__global__ __launch_bounds__(1024) void k_topk(const float* __restrict__ score, const float* __restrict__ h,
                                               float* __restrict__ xbout) {
    __shared__ float sv[2048];
    __shared__ int si[2048];
    __shared__ float red[8][128];
    int g = blockIdx.x, tid = threadIdx.x;
    for (int i = tid; i < 2048; i += 1024) {
        sv[i] = (i < NPG) ? score[g * NPG + i] : -2.0f;  // scores in [-1,1]
        si[i] = i;
    }
    __syncthreads();
    for (int k = 2; k <= 2048; k <<= 1) {
        for (int j = k >> 1; j > 0; j >>= 1) {
            for (int t = tid; t < 2048; t += 1024) {
                int ixj = t ^ j;
                if (ixj > t) {
                    bool up = ((t & k) == 0);  // descending overall
                    float a = sv[t], b = sv[ixj];
                    bool sw = up ? (a < b) : (a > b);
                    if (sw) {
                        sv[t] = b; sv[ixj] = a;
                        int tmp = si[t]; si[t] = si[ixj]; si[ixj] = tmp;
                    }
                }
            }
            __syncthreads();
        }
    }
    int grp = tid >> 7, c = tid & 127;
    float a = 0.f;
    for (int kk = grp; kk < KK; kk += 8) {
        int node = g * NPG + si[kk];
        a += sv[kk] * h[(size_t)node * CC + c];
    }
    red[grp][c] = a;
    __syncthreads();
    if (tid < 128) {
        float v = (red[0][tid] + red[1][tid] + red[2][tid] + red[3][tid] +
                   red[4][tid] + red[5][tid] + red[6][tid] + red[7][tid]) * (1.f / KK);
        xbout[g * CC + tid] = v;
    }
}

// ---------------- final MLP ----------------
__global__ __launch_bounds__(128) void k_mlp(const float* __restrict__ xb, const float* __restrict__ W1,
                                             const float* __restrict__ b1, const float* __restrict__ W2,
                                             const float* __restrict__ b2, const float* __restrict__ Wo,
                                             const float* __restrict__ bo, float* __restrict__ out) {
    int g = blockIdx.x, tid = threadIdx.x;
    __shared__ float xc[256], l1[128], l2[64];
    xc[tid] = xb[g * CC + tid];
    xc[128 + tid] = xb[BB * CC + g * CC + tid];
    __syncthreads();
    float s = b1[tid];
    for (int i = 0; i < 256; i++) s += xc[i] * W1[i * 128 + tid];
    l1[tid] = (s > 0.f) ? s : 0.1f * s;
    __syncthreads();
    if (tid < 64) {
        float s2 = b2[tid];
        for (int i = 0; i < 128; i++) s2 += l1[i] * W2[i * 64 + tid];
        l2[tid] = (s2 > 0.f) ? s2 : 0.1f * s2;
    }
    __syncthreads();
    if (tid < 64) {
        float p = l2[tid] * Wo[tid];
#pragma unroll
        for (int m = 32; m; m >>= 1) p += __shfl_xor(p, m);
        if (tid == 0) out[g] = 1.f / (1.f + __expf(-(p + bo[0])));
    }
}

extern "C" void kernel_launch(void* const* d_in, const int* in_sizes, int n_in,
                              void* d_out, int out_size, void* d_ws, size_t ws_size,
                              hipStream_t stream) {
    (void)in_sizes; (void)n_in; (void)out_size; (void)ws_size;
    const float* Wl   = (const float*)d_in[6];
    const float* bl   = (const float*)d_in[7];
    const float* Wr   = (const float*)d_in[8];
    const float* We   = (const float*)d_in[9];
    const float* att  = (const float*)d_in[10];
    const float* cb   = (const float*)d_in[11];
    const float* gam  = (const float*)d_in[12];
    const float* bet  = (const float*)d_in[13];
    const float* wrel = (const float*)d_in[14];
    const float* wroot= (const float*)d_in[15];
    const float* gcb  = (const float*)d_in[16];
    const float* W1   = (const float*)d_in[17];
    const float* b1   = (const float*)d_in[18];
    const float* W2   = (const float*)d_in[19];
    const float* b2   = (const float*)d_in[20];
    const float* Wo   = (const float*)d_in[21];
    const float* bo   = (const float*)d_in[22];

    float* ws = (float*)d_ws;
    float*  xl    = ws + XL_OFF;
    float*  xr    = ws + XR_OFF;
    float*  hbn   = ws + HBN_OFF;
    int*    ssrc  = (int*)(ws + SSRC_OFF);
    float2* sea   = (float2*)(ws + SEA_OFF);
    int*    cnt   = (int*)(ws + CNT_OFF);
    float*  bnsum = ws + BNSUM_OFF;
    float*  bnsq  = ws + BNSQ_OFF;
    float*  meanea= ws + MEANEA_OFF;
    int*    offs  = (int*)(ws + OFFS_OFF);
    int*    cur   = (int*)(ws + CUR_OFF);
    float*  r_    = ws + R_OFF;
    float*  rel_  = ws + REL_OFF;
    float*  score = ws + SCORE_OFF;
    float*  xb    = ws + XB_OFF;
    unsigned short* Ah  = (unsigned short*)(ws + AH_OFF);
    unsigned short* Al2 = (unsigned short*)(ws + AL_OFF);
    unsigned short* Wth = (unsigned short*)(ws + WTH_OFF);
    unsigned short* Wtl = (unsigned short*)(ws + WTL_OFF);

    k_cvtW<<<(768 * (KP / 8) + 255) / 256, 256, 0, stream>>>(Wl, Wr, Wth, Wtl);

    for (int br = 0; br < 2; br++) {
        const float* x  = (const float*)d_in[br];
        const int*   ei = (const int*)d_in[2 + br];
        const float* ea = (const float*)d_in[4 + br];

        hipMemsetAsync(cnt, 0, ZERO_BYTES, stream);  // cnt + bnsum + bnsq + meanea

        k_prep<<<EE / 256, 256, 0, stream>>>(ei, ea, cnt, meanea);
        k_scan<<<1, 1024, 0, stream>>>(cnt, offs, cur);
        k_scatter<<<EE / 256, 256, 0, stream>>>(ei, ea, cur, ssrc, sea);

        k_cvtA<<<(NN * (KP / 8) + 255) / 256, 256, 0, stream>>>(x, Ah, Al2);
        k_gemm2<<<1504, 256, 0, stream>>>(Ah, Al2, Wth, Wtl, bl, xl, xr);

        k_gat<<<NN / 4, 256, 0, stream>>>(xl, xr, offs, ssrc, sea, meanea, We, att, cb, hbn);

        k_bnstats<<<512, 256, 0, stream>>>(hbn, bnsum, bnsq);
        k_bnapply<<<NN / 4, 256, 0, stream>>>(hbn, bnsum, bnsq, gam, bet, wroot, wrel, r_, rel_);
        k_score<<<NN / 4, 256, 0, stream>>>(r_, rel_, offs, ssrc, gcb, score);
        k_topk<<<BB, 1024, 0, stream>>>(score, hbn, xb + br * BB * CC);
    }
    k_mlp<<<BB, 128, 0, stream>>>(xb, W1, b1, W2, b2, Wo, bo, (float*)d_out);
}

// Round 4
// 1397.528 us; speedup vs baseline: 2.1470x; 1.2149x over previous
//
#include <hip/hip_runtime.h>
#include <hip/hip_bf16.h>
#include <math.h>

#define NN 32000        // total nodes
#define EE 640000       // edges
#define CC 128          // hidden
#define HC 384          // H*C
#define FIN 1038
#define KP 1056         // FIN padded to multiple of 32
#define KT 33           // KP/32
#define BB 16           // graphs
#define NPG 2000
#define KK 400

// per-branch strides (float elements)
#define XLR_STR 12288000u
#define HBN_STR 4096000u
#define OFF_STR 32064u

// ---------------- workspace layout (float elements), 2 branches resident ----------------
#define XL_OFF     0u            // 2 * 12288000
#define XR_OFF     24576000u     // 2 * 12288000
#define HBN_OFF    49152000u     // 2 * 4096000
#define SSRC_OFF   57344000u     // 2 * 640000 (int)
#define SEA_OFF    58624000u     // 2 * 1280000 (float2)
#define CNT_OFF    61184000u     // zero block: cnt(2*32000)+bnsum(2*128)+bnsq(2*128)+meanea(4)
#define BNSUM_OFF  61248000u
#define BNSQ_OFF   61248256u
#define MEANEA_OFF 61248512u
#define ZERO_BYTES ((61248516u - 61184000u) * 4u)
#define OFFS_OFF   61248576u     // 2 * 32064
#define CUR_OFF    61312704u     // 2 * 32000
#define R_OFF      61376704u     // 2 * 32000
#define REL_OFF    61440704u     // 2 * 32000
#define SCORE_OFF  61504704u     // 2 * 32000
#define XB_OFF     61568704u     // 4096
#define WTH_OFF    61572800u     // 405504
#define WTL_OFF    61978304u     // 405504  (end 62383808 fl = 249.5 MB)

typedef __attribute__((ext_vector_type(8))) short bf16x8;
typedef __attribute__((ext_vector_type(4))) float f32x4;
typedef __attribute__((ext_vector_type(8))) unsigned short us8;
typedef __attribute__((ext_vector_type(4))) unsigned int u32x4;

typedef const __attribute__((address_space(1))) unsigned int* gp1_t;
typedef __attribute__((address_space(3))) unsigned int* lp3_t;
__device__ __forceinline__ void gl_lds16(const void* g, void* l) {
    __builtin_amdgcn_global_load_lds((gp1_t)g, (lp3_t)l, 16, 0, 0);
}

// ---------------- fused: dst histogram + edge-attr mean (both branches) ----------------
__global__ __launch_bounds__(256) void k_prep(const int* __restrict__ ei0, const int* __restrict__ ei1,
                                              const float* __restrict__ ea0, const float* __restrict__ ea1,
                                              int* __restrict__ cnt, float* __restrict__ meanea) {
    int b = blockIdx.x;
    int br = (b >= 2500);
    int tid = threadIdx.x;
    int e = (b - br * 2500) * 256 + tid;
    const int* ei = br ? ei1 : ei0;
    const float* ea = br ? ea1 : ea0;
    cnt += br * NN; meanea += br * 2;
    float s0 = 0.f, s1 = 0.f;
    if (e < EE) {
        atomicAdd(&cnt[ei[EE + e]], 1);
        float2 t = ((const float2*)ea)[e];
        s0 = t.x; s1 = t.y;
    }
    __shared__ float r0[256], r1[256];
    r0[tid] = s0; r1[tid] = s1; __syncthreads();
    for (int st = 128; st; st >>= 1) {
        if (tid < st) { r0[tid] += r0[tid + st]; r1[tid] += r1[tid + st]; }
        __syncthreads();
    }
    if (tid == 0) { atomicAdd(&meanea[0], r0[0]); atomicAdd(&meanea[1], r1[0]); }
}

// ---------------- exclusive scan over 32000 counters (1 block per branch) ----------------
__global__ __launch_bounds__(1024) void k_scan(const int* __restrict__ cnt, int* __restrict__ offs, int* __restrict__ cur) {
    int br = blockIdx.x;
    cnt += br * NN; offs += br * OFF_STR; cur += br * NN;
    __shared__ int sb[1024];
    int tid = threadIdx.x;
    int base = tid * 32;
    int s = 0;
    for (int i = 0; i < 32; i++) { int idx = base + i; s += (idx < NN) ? cnt[idx] : 0; }
    sb[tid] = s; __syncthreads();
    for (int off = 1; off < 1024; off <<= 1) {
        int v = (tid >= off) ? sb[tid - off] : 0;
        __syncthreads();
        sb[tid] += v;
        __syncthreads();
    }
    int run = sb[tid] - s;  // exclusive prefix
    for (int i = 0; i < 32; i++) {
        int idx = base + i;
        if (idx < NN) { int c = cnt[idx]; offs[idx] = run; cur[idx] = run; run += c; }
    }
    if (tid == 1023) offs[NN] = run;
}

// ---------------- scatter edges sorted by dst (both branches) ----------------
__global__ __launch_bounds__(256) void k_scatter(const int* __restrict__ ei0, const int* __restrict__ ei1,
                                                 const float* __restrict__ ea0, const float* __restrict__ ea1,
                                                 int* __restrict__ cur, int* __restrict__ ssrc, float2* __restrict__ sea) {
    int b = blockIdx.x;
    int br = (b >= 2500);
    int e = (b - br * 2500) * 256 + threadIdx.x;
    const int* ei = br ? ei1 : ei0;
    const float* ea = br ? ea1 : ea0;
    cur += br * NN; ssrc += br * EE; sea += br * EE;
    if (e < EE) {
        int d = ei[EE + e];
        int p = atomicAdd(&cur[d], 1);
        ssrc[p] = ei[e];
        sea[p] = ((const float2*)ea)[e];
    }
}

// ---------------- weights: transpose to N-major [768][1056], split bf16 ----------------
__global__ __launch_bounds__(256) void k_cvtW(const float* __restrict__ Wl_, const float* __restrict__ Wr_,
                                              unsigned short* __restrict__ Bh, unsigned short* __restrict__ Bl) {
    int idx = blockIdx.x * 256 + threadIdx.x;
    if (idx >= 768 * (KP / 8)) return;
    int n = idx / (KP / 8);
    int seg = idx - n * (KP / 8);
    int c0 = seg * 8;
    const float* W = (n < HC) ? Wl_ : Wr_;
    int nc = (n < HC) ? n : n - HC;
    us8 h8, l8;
#pragma unroll
    for (int j = 0; j < 8; ++j) {
        int k = c0 + j;
        float v = (k < FIN) ? W[(size_t)k * HC + nc] : 0.f;
        unsigned b = __float_as_uint(v);
        unsigned hb = b & 0xffff0000u;
        float res = v - __uint_as_float(hb);
        h8[j] = (unsigned short)(hb >> 16);
        l8[j] = (unsigned short)(__float_as_uint(res) >> 16);
    }
    *(us8*)&Bh[(size_t)n * KP + c0] = h8;
    *(us8*)&Bl[(size_t)n * KP + c0] = l8;
}

// ---------------- MFMA GEMM with fused fp32->split-bf16 A conversion, both branches ----------------
// C[32000,768] = x[32000,1038(pad1056)] @ Wt^T, 3-term bf16 split: Ah*Bh + Ah*Bl + Al*Bh.
// Grid 3008: [0,1504) branch 0, [1504,3008) branch 1; per-branch XCD-aware remap keeps all
// 6 N-tiles of an M-tile on one XCD. A staged from fp32 x directly (float2 loads, in-reg
// hi/lo split via v_perm, ds_write_b128 into the same sAh/sAl layout as before).
__global__ __launch_bounds__(256) void k_gemm2f(const float* __restrict__ x0, const float* __restrict__ x1,
                                                const unsigned short* __restrict__ Bh, const unsigned short* __restrict__ Bl,
                                                const float* __restrict__ bias, float* __restrict__ ws) {
    __shared__ unsigned short sAh[128 * 32], sAl[128 * 32], sBh[128 * 32], sBl[128 * 32];
    const int bid = blockIdx.x;
    const int br = (bid >= 1504);
    const int b2 = br ? (bid - 1504) : bid;
    const float* x = br ? x1 : x0;
    float* xl = ws + XL_OFF + br * XLR_STR;
    float* xr = ws + XR_OFF + br * XLR_STR;

    const int xcd = b2 & 7, slot = b2 >> 3;
    const int t = xcd * 188 + slot;          // 1504/8 = 188 slots per XCD
    if (t >= 1500) return;
    const int mt = t / 6, nt = t - mt * 6;
    const int bm = mt * 128, bn = nt * 128;

    const int tid = threadIdx.x;
    const int wave = tid >> 6, lane = tid & 63;
    const int wm = (wave >> 1) * 64, wn = (wave & 1) * 64;
    const int quad = lane >> 4, l15 = lane & 15;

    // B staging (global_load_lds, bf16 pre-split)
    const int srow = wave * 16 + (lane >> 2);
    const int scol = (lane & 3) * 8;
    const size_t gB0 = (size_t)(bn + srow) * KP + scol;
    const size_t gB1 = (size_t)(bn + 64 + srow) * KP + scol;
    const int lB0 = (wave * 16) * 32 + lane * 8;
    const int lB1 = (64 + wave * 16) * 32 + lane * 8;

    // A staging (fp32 loads -> split -> ds_write): wave w covers rows w*32..w*32+31
    const int arow0 = wave * 32 + (lane >> 2);   // + rep*16
    const int acol = (lane & 3) * 8;             // 8 fp32 per lane per rep

    f32x4 acc[4][4];
#pragma unroll
    for (int i = 0; i < 4; ++i)
#pragma unroll
        for (int j = 0; j < 4; ++j) {
            f32x4 z = {0.f, 0.f, 0.f, 0.f};
            acc[i][j] = z;
        }

    const int aoff0 = (wm + l15) * 32 + quad * 8;   // + i*512
    const int boff0 = (wn + l15) * 32 + quad * 8;   // + j*512

    for (int kt = 0; kt < KT; ++kt) {
        const int kc = kt * 32;
        gl_lds16(Bh + gB0 + kc, &sBh[lB0]);
        gl_lds16(Bh + gB1 + kc, &sBh[lB1]);
        gl_lds16(Bl + gB0 + kc, &sBl[lB0]);
        gl_lds16(Bl + gB1 + kc, &sBl[lB1]);
        // A: load 8 fp32, split to hi/lo bf16, write to LDS (pure-pad chunks clamp to col 0;
        // garbage cols multiply B's zeroed pad -> contribute 0)
        int gcol = kc + acol;
        if (gcol >= FIN) gcol = 0;
#pragma unroll
        for (int rep = 0; rep < 2; ++rep) {
            const int lrow = arow0 + rep * 16;
            const float* gp = x + (size_t)(bm + lrow) * FIN + gcol;
            float2 v01 = ((const float2*)gp)[0];
            float2 v23 = ((const float2*)gp)[1];
            float2 v45 = ((const float2*)gp)[2];
            float2 v67 = ((const float2*)gp)[3];
            float f[8] = {v01.x, v01.y, v23.x, v23.y, v45.x, v45.y, v67.x, v67.y};
            u32x4 hi, lo;
#pragma unroll
            for (int j = 0; j < 4; ++j) {
                unsigned u0 = __float_as_uint(f[2 * j]);
                unsigned u1 = __float_as_uint(f[2 * j + 1]);
                float r0 = f[2 * j]     - __uint_as_float(u0 & 0xffff0000u);
                float r1 = f[2 * j + 1] - __uint_as_float(u1 & 0xffff0000u);
                hi[j] = __builtin_amdgcn_perm(u1, u0, 0x07060302u);
                lo[j] = __builtin_amdgcn_perm(__float_as_uint(r1), __float_as_uint(r0), 0x07060302u);
            }
            const int lidx = lrow * 32 + acol;   // ushort units, 16B-aligned
            *(u32x4*)&sAh[lidx] = hi;
            *(u32x4*)&sAl[lidx] = lo;
        }
        __syncthreads();   // drains vmcnt (B DMA) + lgkmcnt (A ds_write)
        bf16x8 bh[4], blo[4];
#pragma unroll
        for (int j = 0; j < 4; ++j) {
            bh[j]  = *(const bf16x8*)&sBh[boff0 + j * 512];
            blo[j] = *(const bf16x8*)&sBl[boff0 + j * 512];
        }
#pragma unroll
        for (int i = 0; i < 4; ++i) {
            bf16x8 ah = *(const bf16x8*)&sAh[aoff0 + i * 512];
            bf16x8 al = *(const bf16x8*)&sAl[aoff0 + i * 512];
#pragma unroll
            for (int j = 0; j < 4; ++j) {
                acc[i][j] = __builtin_amdgcn_mfma_f32_16x16x32_bf16(ah, bh[j],  acc[i][j], 0, 0, 0);
                acc[i][j] = __builtin_amdgcn_mfma_f32_16x16x32_bf16(ah, blo[j], acc[i][j], 0, 0, 0);
                acc[i][j] = __builtin_amdgcn_mfma_f32_16x16x32_bf16(al, bh[j],  acc[i][j], 0, 0, 0);
            }
        }
        __syncthreads();   // protect LDS before next stage
    }

    // epilogue: C/D layout col=lane&15, row=quad*4+reg. Block is purely xl or purely xr.
    const bool isL = (nt < 3);
    float* outp = isL ? xl : xr;
    const int nbase = isL ? bn : (bn - HC);
#pragma unroll
    for (int j = 0; j < 4; ++j) {
        const int ncol = wn + j * 16 + l15;
        const float bj = isL ? bias[bn + ncol] : 0.f;
#pragma unroll
        for (int i = 0; i < 4; ++i) {
#pragma unroll
            for (int r = 0; r < 4; ++r) {
                int m = bm + wm + i * 16 + quad * 4 + r;
                outp[(size_t)m * HC + nbase + ncol] = acc[i][j][r] + bj;
            }
        }
    }
}

// ---------------- fused GATv2 per-dst aggregation (one wave per node, both branches) ----------------
__global__ __launch_bounds__(256) void k_gat(const float* __restrict__ xlb, const float* __restrict__ xrb,
                                             const int* __restrict__ offsb, const int* __restrict__ ssrcb,
                                             const float2* __restrict__ seab, const float* __restrict__ meaneab,
                                             const float* __restrict__ We, const float* __restrict__ att,
                                             const float* __restrict__ conv_bias, float* __restrict__ houtb) {
    int gwave = (blockIdx.x * 256 + threadIdx.x) >> 6;
    int lane = threadIdx.x & 63;
    int br = (gwave >= NN);
    int wave = gwave - br * NN;
    const float* xl = xlb + br * XLR_STR;
    const float* xr = xrb + br * XLR_STR;
    const int* offs = offsb + br * OFF_STR;
    const int* ssrc = ssrcb + br * EE;
    const float2* sea = seab + br * EE;
    const float* meanea = meaneab + br * 2;
    float* hout = houtb + br * HBN_STR;

    float we0[6], we1[6], attv[6], xrv[6];
#pragma unroll
    for (int j = 0; j < 6; j++) {
        int i = j * 64 + lane;
        we0[j] = We[i]; we1[j] = We[HC + i]; attv[j] = att[i];
        xrv[j] = xr[(size_t)wave * HC + i];
    }
    float me0 = meanea[0] * (1.0f / EE), me1 = meanea[1] * (1.0f / EE);
    float acc[6] = {0, 0, 0, 0, 0, 0};
    float den0 = 0, den1 = 0, den2 = 0;
    int p0 = offs[wave], p1 = offs[wave + 1];
    for (int p = p0 - 1; p < p1; ++p) {
        int s; float ea0, ea1;
        if (p < p0) { s = wave; ea0 = me0; ea1 = me1; }   // self loop (fill='mean')
        else { s = ssrc[p]; float2 t = sea[p]; ea0 = t.x; ea1 = t.y; }
        const float* xls = xl + (size_t)s * HC;
        float xv[6], pr0 = 0, pr1 = 0, pr2 = 0;
#pragma unroll
        for (int j = 0; j < 6; j++) {
            float v = xls[j * 64 + lane];
            xv[j] = v;
            float m = v + xrv[j] + ea0 * we0[j] + ea1 * we1[j];
            float t = (m > 0.f) ? m : 0.2f * m;
            float c = t * attv[j];
            if (j < 2) pr0 += c; else if (j < 4) pr1 += c; else pr2 += c;
        }
#pragma unroll
        for (int mask = 32; mask; mask >>= 1) {
            pr0 += __shfl_xor(pr0, mask);
            pr1 += __shfl_xor(pr1, mask);
            pr2 += __shfl_xor(pr2, mask);
        }
        float w0 = __expf(pr0), w1 = __expf(pr1), w2 = __expf(pr2);
        den0 += w0; den1 += w1; den2 += w2;
        acc[0] += w0 * xv[0]; acc[1] += w0 * xv[1];
        acc[2] += w1 * xv[2]; acc[3] += w1 * xv[3];
        acc[4] += w2 * xv[4]; acc[5] += w2 * xv[5];
    }
    float i0 = 1.f / den0, i1 = 1.f / den1, i2 = 1.f / den2;
    float o0 = (acc[0] * i0 + acc[2] * i1 + acc[4] * i2) * (1.f / 3.f) + conv_bias[lane];
    float o1 = (acc[1] * i0 + acc[3] * i1 + acc[5] * i2) * (1.f / 3.f) + conv_bias[64 + lane];
    o0 = (o0 > 0.f) ? o0 : 0.1f * o0;
    o1 = (o1 > 0.f) ? o1 : 0.1f * o1;
    hout[(size_t)wave * CC + lane] = o0;
    hout[(size_t)wave * CC + 64 + lane] = o1;
}

// ---------------- batchnorm stats (both branches) ----------------
__global__ __launch_bounds__(256) void k_bnstats(const float* __restrict__ hb, float* __restrict__ bnsumb, float* __restrict__ bnsqb) {
    int b = blockIdx.x;
    int br = b >> 9, lb = b & 511;
    const float* h = hb + br * HBN_STR;
    float* bnsum = bnsumb + br * CC;
    float* bnsq = bnsqb + br * CC;
    int c = threadIdx.x & 127;
    int row0 = lb * 2 + (threadIdx.x >> 7);
    float s = 0.f, ss = 0.f;
    for (int n = row0; n < NN; n += 1024) {
        float v = h[(size_t)n * CC + c];
        s += v; ss += v * v;
    }
    atomicAdd(&bnsum[c], s);
    atomicAdd(&bnsq[c], ss);
}

// ---------------- BN apply (folds bnfinal) + scorer dot products (both branches) ----------------
__global__ __launch_bounds__(256) void k_bnapply(float* __restrict__ hb, const float* __restrict__ bnsumb,
                                                 const float* __restrict__ bnsqb,
                                                 const float* __restrict__ gamma, const float* __restrict__ beta,
                                                 const float* __restrict__ wroot,
                                                 const float* __restrict__ wrel, float* __restrict__ r_b, float* __restrict__ rel_b) {
    int gwave = (blockIdx.x * 256 + threadIdx.x) >> 6;
    int lane = threadIdx.x & 63;
    int br = (gwave >= NN);
    int wave = gwave - br * NN;
    float* h = hb + br * HBN_STR;
    const float* bnsum = bnsumb + br * CC;
    const float* bnsq = bnsqb + br * CC;
    float* r_ = r_b + br * NN;
    float* rel_ = rel_b + br * NN;

    float mu0 = bnsum[lane] * (1.f / NN);
    float var0 = bnsq[lane] * (1.f / NN) - mu0 * mu0;
    float sc0 = gamma[lane] * rsqrtf(var0 + 1e-5f);
    float sh0 = beta[lane] - mu0 * sc0;
    float mu1 = bnsum[64 + lane] * (1.f / NN);
    float var1 = bnsq[64 + lane] * (1.f / NN) - mu1 * mu1;
    float sc1 = gamma[64 + lane] * rsqrtf(var1 + 1e-5f);
    float sh1 = beta[64 + lane] - mu1 * sc1;

    size_t base = (size_t)wave * CC;
    float v0 = h[base + lane], v1 = h[base + 64 + lane];
    v0 = v0 * sc0 + sh0;
    v1 = v1 * sc1 + sh1;
    h[base + lane] = v0;
    h[base + 64 + lane] = v1;
    float pr = v0 * wroot[lane] + v1 * wroot[64 + lane];
    float pl = v0 * wrel[lane] + v1 * wrel[64 + lane];
#pragma unroll
    for (int m = 32; m; m >>= 1) {
        pr += __shfl_xor(pr, m);
        pl += __shfl_xor(pl, m);
    }
    if (lane == 0) { r_[wave] = pr; rel_[wave] = pl; }
}

// ---------------- scorer aggregation + tanh (both branches) ----------------
__global__ __launch_bounds__(256) void k_score(const float* __restrict__ r_b, const float* __restrict__ rel_b,
                                               const int* __restrict__ offsb, const int* __restrict__ ssrcb,
                                               const float* __restrict__ gcb, float* __restrict__ scoreb) {
    int gwave = (blockIdx.x * 256 + threadIdx.x) >> 6;
    int lane = threadIdx.x & 63;
    int br = (gwave >= NN);
    int wave = gwave - br * NN;
    const float* r_ = r_b + br * NN;
    const float* rel_ = rel_b + br * NN;
    const int* offs = offsb + br * OFF_STR;
    const int* ssrc = ssrcb + br * EE;
    float* score = scoreb + br * NN;
    int p0 = offs[wave], p1 = offs[wave + 1];
    float s = 0.f;
    for (int p = p0 + lane; p < p1; p += 64) s += rel_[ssrc[p]];
#pragma unroll
    for (int m = 32; m; m >>= 1) s += __shfl_xor(s, m);
    if (lane == 0) score[wave] = tanhf(r_[wave] + s + gcb[0]);
}

// ---------------- per-graph top-K (exact bitonic sort of 2048) + weighted mean pool ----------------
__global__ __launch_bounds__(1024) void k_topk(const float* __restrict__ scoreb, const float* __restrict__ hb,
                                               float* __restrict__ xbout) {
    __shared__ float sv[2048];
    __shared__ int si[2048];
    __shared__ float red[8][128];
    int b = blockIdx.x, tid = threadIdx.x;
    int br = b >> 4, g = b & 15;
    const float* score = scoreb + br * NN;
    const float* h = hb + br * HBN_STR;
    for (int i = tid; i < 2048; i += 1024) {
        sv[i] = (i < NPG) ? score[g * NPG + i] : -2.0f;  // scores in [-1,1]
        si[i] = i;
    }
    __syncthreads();
    for (int k = 2; k <= 2048; k <<= 1) {
        for (int j = k >> 1; j > 0; j >>= 1) {
            for (int t = tid; t < 2048; t += 1024) {
                int ixj = t ^ j;
                if (ixj > t) {
                    bool up = ((t & k) == 0);  // descending overall
                    float a = sv[t], bv = sv[ixj];
                    bool sw = up ? (a < bv) : (a > bv);
                    if (sw) {
                        sv[t] = bv; sv[ixj] = a;
                        int tmp = si[t]; si[t] = si[ixj]; si[ixj] = tmp;
                    }
                }
            }
            __syncthreads();
        }
    }
    int grp = tid >> 7, c = tid & 127;
    float a = 0.f;
    for (int kk = grp; kk < KK; kk += 8) {
        int node = g * NPG + si[kk];
        a += sv[kk] * h[(size_t)node * CC + c];
    }
    red[grp][c] = a;
    __syncthreads();
    if (tid < 128) {
        float v = (red[0][tid] + red[1][tid] + red[2][tid] + red[3][tid] +
                   red[4][tid] + red[5][tid] + red[6][tid] + red[7][tid]) * (1.f / KK);
        xbout[(br * BB + g) * CC + tid] = v;
    }
}

// ---------------- final MLP ----------------
__global__ __launch_bounds__(128) void k_mlp(const float* __restrict__ xb, const float* __restrict__ W1,
                                             const float* __restrict__ b1, const float* __restrict__ W2,
                                             const float* __restrict__ b2, const float* __restrict__ Wo,
                                             const float* __restrict__ bo, float* __restrict__ out) {
    int g = blockIdx.x, tid = threadIdx.x;
    __shared__ float xc[256], l1[128], l2[64];
    xc[tid] = xb[g * CC + tid];
    xc[128 + tid] = xb[BB * CC + g * CC + tid];
    __syncthreads();
    float s = b1[tid];
    for (int i = 0; i < 256; i++) s += xc[i] * W1[i * 128 + tid];
    l1[tid] = (s > 0.f) ? s : 0.1f * s;
    __syncthreads();
    if (tid < 64) {
        float s2 = b2[tid];
        for (int i = 0; i < 128; i++) s2 += l1[i] * W2[i * 64 + tid];
        l2[tid] = (s2 > 0.f) ? s2 : 0.1f * s2;
    }
    __syncthreads();
    if (tid < 64) {
        float p = l2[tid] * Wo[tid];
#pragma unroll
        for (int m = 32; m; m >>= 1) p += __shfl_xor(p, m);
        if (tid == 0) out[g] = 1.f / (1.f + __expf(-(p + bo[0])));
    }
}

extern "C" void kernel_launch(void* const* d_in, const int* in_sizes, int n_in,
                              void* d_out, int out_size, void* d_ws, size_t ws_size,
                              hipStream_t stream) {
    (void)in_sizes; (void)n_in; (void)out_size; (void)ws_size;
    const float* x0   = (const float*)d_in[0];
    const float* x1   = (const float*)d_in[1];
    const int*   ei0  = (const int*)d_in[2];
    const int*   ei1  = (const int*)d_in[3];
    const float* ea0  = (const float*)d_in[4];
    const float* ea1  = (const float*)d_in[5];
    const float* Wl   = (const float*)d_in[6];
    const float* bl   = (const float*)d_in[7];
    const float* Wr   = (const float*)d_in[8];
    const float* We   = (const float*)d_in[9];
    const float* att  = (const float*)d_in[10];
    const float* cb   = (const float*)d_in[11];
    const float* gam  = (const float*)d_in[12];
    const float* bet  = (const float*)d_in[13];
    const float* wrel = (const float*)d_in[14];
    const float* wroot= (const float*)d_in[15];
    const float* gcb  = (const float*)d_in[16];
    const float* W1   = (const float*)d_in[17];
    const float* b1   = (const float*)d_in[18];
    const float* W2   = (const float*)d_in[19];
    const float* b2   = (const float*)d_in[20];
    const float* Wo   = (const float*)d_in[21];
    const float* bo   = (const float*)d_in[22];

    float* ws = (float*)d_ws;
    float*  xl    = ws + XL_OFF;
    float*  xr    = ws + XR_OFF;
    float*  hbn   = ws + HBN_OFF;
    int*    ssrc  = (int*)(ws + SSRC_OFF);
    float2* sea   = (float2*)(ws + SEA_OFF);
    int*    cnt   = (int*)(ws + CNT_OFF);
    float*  bnsum = ws + BNSUM_OFF;
    float*  bnsq  = ws + BNSQ_OFF;
    float*  meanea= ws + MEANEA_OFF;
    int*    offs  = (int*)(ws + OFFS_OFF);
    int*    cur   = (int*)(ws + CUR_OFF);
    float*  r_    = ws + R_OFF;
    float*  rel_  = ws + REL_OFF;
    float*  score = ws + SCORE_OFF;
    float*  xb    = ws + XB_OFF;
    unsigned short* Wth = (unsigned short*)(ws + WTH_OFF);
    unsigned short* Wtl = (unsigned short*)(ws + WTL_OFF);

    hipMemsetAsync(cnt, 0, ZERO_BYTES, stream);  // cnt + bnsum + bnsq + meanea, both branches
    k_cvtW<<<(768 * (KP / 8) + 255) / 256, 256, 0, stream>>>(Wl, Wr, Wth, Wtl);

    k_prep<<<5000, 256, 0, stream>>>(ei0, ei1, ea0, ea1, cnt, meanea);
    k_scan<<<2, 1024, 0, stream>>>(cnt, offs, cur);
    k_scatter<<<5000, 256, 0, stream>>>(ei0, ei1, ea0, ea1, cur, ssrc, sea);

    k_gemm2f<<<3008, 256, 0, stream>>>(x0, x1, Wth, Wtl, bl, ws);

    k_gat<<<16000, 256, 0, stream>>>(xl, xr, offs, ssrc, sea, meanea, We, att, cb, hbn);

    k_bnstats<<<1024, 256, 0, stream>>>(hbn, bnsum, bnsq);
    k_bnapply<<<16000, 256, 0, stream>>>(hbn, bnsum, bnsq, gam, bet, wroot, wrel, r_, rel_);
    k_score<<<16000, 256, 0, stream>>>(r_, rel_, offs, ssrc, gcb, score);
    k_topk<<<32, 1024, 0, stream>>>(score, hbn, xb);

    k_mlp<<<BB, 128, 0, stream>>>(xb, W1, b1, W2, b2, Wo, bo, (float*)d_out);
}